// Round 18
// baseline (272.844 us; speedup 1.0000x reference)
//
#include <hip/hip_runtime.h>

#define K_IN   256
#define C_OUT  256
#define HEADS  4
#define PAD    64    // csr slots per node (P(deg>64) ~ 1e-13 for Poisson(16))
#define BKT    256   // dst nodes per bucket
#define REP    16    // cursor replicas per bucket
#define CAP    448   // stage capacity per (bucket, replica); avg fill ~256

typedef __attribute__((ext_vector_type(8))) short s16x8;
typedef __attribute__((ext_vector_type(4))) short s16x4;
typedef __attribute__((ext_vector_type(4))) float f32x4;
typedef __attribute__((ext_vector_type(4))) int   i32x4;

static __device__ __forceinline__ unsigned short f2bf(float f) {
  union { float f; unsigned u; } v; v.f = f;
  unsigned r = v.u + 0x7FFFu + ((v.u >> 16) & 1u);
  return (unsigned short)(r >> 16);
}
static __device__ __forceinline__ float bf2f(unsigned short u) {
  union { unsigned u; float f; } v; v.u = (unsigned)u << 16;
  return v.f;
}
static __device__ __forceinline__ unsigned cvt_pk_bf16(float lo, float hi) {
  unsigned r;
  asm volatile("v_cvt_pk_bf16_f32 %0, %1, %2" : "=v"(r) : "v"(lo), "v"(hi));
  return r;
}
static __device__ __forceinline__ float fast_exp2(float x) {
  float r;
  asm("v_exp_f32 %0, %1" : "=v"(r) : "v"(x));
  return r;
}

// ---------------------------------------------------------------------------
// W (fp32 [c=256][k=256], c=head*64+out) -> k-slice-contiguous fragment bf16:
// Wf2[ks*8192 + cb*2048 + s*512 + lane*8 + j]
//   = W[cb*64+s*16+(lane&15)][ks*32+(lane>>4)*8+j]
// ---------------------------------------------------------------------------
__global__ void cvt_w(const float* __restrict__ Wm, unsigned short* __restrict__ Wf2) {
  int idx = blockIdx.x * blockDim.x + threadIdx.x;
  if (idx >= 65536) return;
  int j    = idx & 7;
  int lane = (idx >> 3) & 63;
  int s    = (idx >> 9) & 3;
  int cb   = (idx >> 11) & 3;
  int ks   = (idx >> 13) & 7;
  int c = cb * 64 + s * 16 + (lane & 15);
  int k = ks * 32 + (lane >> 4) * 8 + j;
  Wf2[idx] = f2bf(Wm[c * K_IN + k]);
}

// ---------------------------------------------------------------------------
// GEMM body (row-split, LDS-staged B, full A-row prefetch) — R17-proven.
// ---------------------------------------------------------------------------
static __device__ __forceinline__ void gemm_body(int bid,
    const float* __restrict__ h, const unsigned short* __restrict__ Wf2,
    const float* __restrict__ attn, unsigned short* __restrict__ zb,
    float* __restrict__ ssrc, float* __restrict__ sdst, int n_nodes,
    s16x8 (*lds_b)[1024]) {
  const int tid  = threadIdx.x;
  const int lane = tid & 63;
  const int l15  = lane & 15;
  const int lhi  = lane >> 4;
  const int r0   = bid * 64 + (tid >> 6) * 16;

  f32x4 acc[16];
#pragma unroll
  for (int f = 0; f < 16; ++f) acc[f] = (f32x4){0.f, 0.f, 0.f, 0.f};

  int n = r0 + l15;
  if (n > n_nodes - 1) n = n_nodes - 1;
  const long long arow = (long long)n * K_IN;
  const int kbase = lhi * 8;

  // prefetch all 8 A slices (16 independent float4 loads in flight)
  float4 va[8][2];
#pragma unroll
  for (int ks = 0; ks < 8; ++ks) {
    const float4* ps = reinterpret_cast<const float4*>(h + arow + ks * 32 + kbase);
    va[ks][0] = ps[0];
    va[ks][1] = ps[1];
  }
  // stage B slice 0 while A-loads fly
  {
    const s16x8* src = reinterpret_cast<const s16x8*>(Wf2);
#pragma unroll
    for (int r = 0; r < 4; ++r) lds_b[0][tid + r * 256] = src[tid + r * 256];
  }
  // convert A to bf16 fragments
  s16x8 afr[8];
#pragma unroll
  for (int ks = 0; ks < 8; ++ks) {
    union { s16x8 v; unsigned u[4]; } au;
    au.u[0] = cvt_pk_bf16(va[ks][0].x, va[ks][0].y);
    au.u[1] = cvt_pk_bf16(va[ks][0].z, va[ks][0].w);
    au.u[2] = cvt_pk_bf16(va[ks][1].x, va[ks][1].y);
    au.u[3] = cvt_pk_bf16(va[ks][1].z, va[ks][1].w);
    afr[ks] = au.v;
  }
  __syncthreads();

#pragma unroll
  for (int ks = 0; ks < 8; ++ks) {
    const int cur = ks & 1;
    s16x8 st[4];
    if (ks < 7) {
      const s16x8* src = reinterpret_cast<const s16x8*>(Wf2 + (ks + 1) * 8192);
#pragma unroll
      for (int r = 0; r < 4; ++r) st[r] = src[tid + r * 256];
    }
#pragma unroll
    for (int f = 0; f < 16; ++f) {
      s16x8 b = lds_b[cur][f * 64 + lane];
      acc[f] = __builtin_amdgcn_mfma_f32_16x16x32_bf16(afr[ks], b, acc[f], 0, 0, 0);
    }
    if (ks < 7) {
#pragma unroll
      for (int r = 0; r < 4; ++r) lds_b[cur ^ 1][tid + r * 256] = st[r];
      __syncthreads();
    }
  }

  // epilogue 1: bf16 z store
#pragma unroll
  for (int reg = 0; reg < 4; ++reg) {
    int row = r0 + lhi * 4 + reg;
    if (row < n_nodes) {
#pragma unroll
      for (int f = 0; f < 16; ++f)
        zb[(size_t)row * C_OUT + f * 16 + l15] = f2bf(acc[f][reg]);
    }
  }

  // epilogue 2: per-head scores, log2e-prescaled
  const float LOG2E = 1.4426950408889634f;
  float as_[4], ad_[4];
#pragma unroll
  for (int s = 0; s < 4; ++s) {
    as_[s] = attn[s * 16 + l15];
    ad_[s] = attn[64 + s * 16 + l15];
  }
#pragma unroll
  for (int reg = 0; reg < 4; ++reg) {
    int row = r0 + lhi * 4 + reg;
    float ps[4], pd[4];
#pragma unroll
    for (int hd = 0; hd < 4; ++hd) {
      ps[hd] = acc[hd * 4 + 0][reg] * as_[0] + acc[hd * 4 + 1][reg] * as_[1] +
               acc[hd * 4 + 2][reg] * as_[2] + acc[hd * 4 + 3][reg] * as_[3];
      pd[hd] = acc[hd * 4 + 0][reg] * ad_[0] + acc[hd * 4 + 1][reg] * ad_[1] +
               acc[hd * 4 + 2][reg] * ad_[2] + acc[hd * 4 + 3][reg] * ad_[3];
#pragma unroll
      for (int d = 1; d < 16; d <<= 1) {
        ps[hd] += __shfl_xor(ps[hd], d, 64);
        pd[hd] += __shfl_xor(pd[hd], d, 64);
      }
    }
    if (l15 == 0 && row < n_nodes) {
#pragma unroll
      for (int hd = 0; hd < 4; ++hd) {
        ssrc[(size_t)row * 4 + hd] = ps[hd] * LOG2E;
        sdst[(size_t)row * 4 + hd] = pd[hd] * LOG2E;
      }
    }
  }
}

// ---------------------------------------------------------------------------
// Scatter-r1 body (R12-proven): 4 edges/thread, append to dst buckets.
// ---------------------------------------------------------------------------
static __device__ __forceinline__ void scatter_body(int sbid,
    const int* __restrict__ src, const int* __restrict__ dst, int E,
    int* __restrict__ cursors, int* __restrict__ stage) {
  int i = sbid * 256 + threadIdx.x;
  int rep = sbid & (REP - 1);
  int e4 = E >> 2;
  if (i < e4) {
    i32x4 d = __builtin_nontemporal_load(reinterpret_cast<const i32x4*>(dst) + i);
    i32x4 s = __builtin_nontemporal_load(reinterpret_cast<const i32x4*>(src) + i);
#pragma unroll
    for (int k = 0; k < 4; ++k) {
      int c = (d[k] >> 8) * REP + rep;
      int p = atomicAdd(&cursors[c], 1);
      if (p < CAP) stage[c * CAP + p] = (s[k] << 8) | (d[k] & 255);
    }
  }
  if (i < (E & 3)) {
    int j = (e4 << 2) + i;
    int dd = dst[j], ss = src[j];
    int c = (dd >> 8) * REP + rep;
    int p = atomicAdd(&cursors[c], 1);
    if (p < CAP) stage[c * CAP + p] = (ss << 8) | (dd & 255);
  }
}

// ---------------------------------------------------------------------------
// Fused dispatch (parity interleave): even blocks gemm, odd scatter.
// ---------------------------------------------------------------------------
__global__ __launch_bounds__(256) void gemm_scatter(
    const float* __restrict__ h, const unsigned short* __restrict__ Wf2,
    const float* __restrict__ attn, unsigned short* __restrict__ zb,
    float* __restrict__ ssrc, float* __restrict__ sdst, int n_nodes,
    int g_gemm, const int* __restrict__ e_src, const int* __restrict__ e_dst,
    int E, int g_scat, int* __restrict__ cursors, int* __restrict__ stage) {
  __shared__ s16x8 lds_b[2][1024];   // 2 x 16 KB B k-slice double buffer
  int bid = blockIdx.x;
  if ((bid & 1) == 0) {
    int g = bid >> 1;
    if (g < g_gemm)
      gemm_body(g, h, Wf2, attn, zb, ssrc, sdst, n_nodes, lds_b);
  } else {
    int s = bid >> 1;
    if (s < g_scat)
      scatter_body(s, e_src, e_dst, E, cursors, stage);
  }
}

// ---------------------------------------------------------------------------
// Binned CSR build, round 2: one block per bucket; LDS counters; L2-dense
// scatter into the bucket's 64KB csrp window. Writes counts[] directly.
// ---------------------------------------------------------------------------
__global__ __launch_bounds__(256) void scatter_r2(const int* __restrict__ cursors,
                                                  const int* __restrict__ stage,
                                                  int N, int* __restrict__ counts,
                                                  int* __restrict__ csrp) {
  int b = blockIdx.x;
  int base = b << 8;
  __shared__ int cnt[BKT];
  for (int i = threadIdx.x; i < BKT; i += 256) cnt[i] = 0;
  __syncthreads();
  for (int rep = 0; rep < REP; ++rep) {
    int c = b * REP + rep;
    int len = min(cursors[c], CAP);
    for (int j = threadIdx.x; j < len; j += 256) {
      int v = stage[c * CAP + j];
      int d = v & 255, s = v >> 8;
      int slot = atomicAdd(&cnt[d], 1);
      if (slot < PAD) csrp[(size_t)(base + d) * PAD + slot] = s;
    }
  }
  __syncthreads();
  for (int i = threadIdx.x; i < BKT; i += 256) {
    int n = base + i;
    if (n < N) counts[n] = min(cnt[i], PAD);
  }
}

// ---------------------------------------------------------------------------
// Fallback: direct padded scatter (R9 path; needs less workspace)
// ---------------------------------------------------------------------------
__global__ void scatter_pad(const int* __restrict__ src, const int* __restrict__ dst,
                            int e, int* __restrict__ cursor, int* __restrict__ csrp) {
  int i = blockIdx.x * blockDim.x + threadIdx.x;
  int e4 = e >> 2;
  if (i < e4) {
    i32x4 d = __builtin_nontemporal_load(reinterpret_cast<const i32x4*>(dst) + i);
    i32x4 s = __builtin_nontemporal_load(reinterpret_cast<const i32x4*>(src) + i);
#pragma unroll
    for (int k = 0; k < 4; ++k) {
      int p = atomicAdd(&cursor[d[k]], 1);
      csrp[d[k] * PAD + p] = s[k];
    }
  }
  if (i < (e & 3)) {
    int j = (e4 << 2) + i;
    int p = atomicAdd(&cursor[dst[j]], 1);
    csrp[dst[j] * PAD + p] = src[j];
  }
}

// ---------------------------------------------------------------------------
// Aggregation: one wave per dst node (grid-stride over nodes), x8-unrolled
// bf16 gather; padded CSR. Single dispatch, 2048 blocks.
// ---------------------------------------------------------------------------
__global__ __launch_bounds__(256) void aggregate(const unsigned short* __restrict__ zb,
                                                 const float* __restrict__ ssrc,
                                                 const float* __restrict__ sdst,
                                                 const int* __restrict__ cnts,
                                                 const int* __restrict__ csr,
                                                 float* __restrict__ out,
                                                 int n_nodes) {
  const int lane = threadIdx.x & 63;
  const int head = lane >> 4;
  const int wstride = gridDim.x * (blockDim.x >> 6);
  for (int w = blockIdx.x * (blockDim.x >> 6) + (threadIdx.x >> 6);
       w < n_nodes; w += wstride) {
    int beg = w * PAD;
    int end = beg + cnts[w];
    float sd = sdst[(size_t)w * 4 + head];
    float ax = 0.f, ay = 0.f, az = 0.f, aw = 0.f;
    float den = 0.f;
    for (int e = beg; e < end; e += 8) {
      int srcs[8];
#pragma unroll
      for (int j = 0; j < 8; ++j) {
        int idx = e + j;
        if (idx >= end) idx = end - 1;
        srcs[j] = __builtin_nontemporal_load(csr + idx);
      }
      float ss[8];
#pragma unroll
      for (int j = 0; j < 8; ++j)
        ss[j] = ssrc[(size_t)srcs[j] * 4 + head];
      s16x4 zv[8];
#pragma unroll
      for (int j = 0; j < 8; ++j)
        zv[j] = *reinterpret_cast<const s16x4*>(zb + (size_t)srcs[j] * C_OUT + lane * 4);
#pragma unroll
      for (int j = 0; j < 8; ++j) {
        float x = ss[j] + sd;
        x = x > 0.f ? x : 0.01f * x;
        float ex = fast_exp2(x);
        ex = (e + j < end) ? ex : 0.f;
        den += ex;
        ax += ex * bf2f((unsigned short)zv[j][0]);
        ay += ex * bf2f((unsigned short)zv[j][1]);
        az += ex * bf2f((unsigned short)zv[j][2]);
        aw += ex * bf2f((unsigned short)zv[j][3]);
      }
    }
    float inv = (end > beg) ? 1.f / fmaxf(den, 1e-9f) : 0.f;
    f32x4 o = {ax * inv, ay * inv, az * inv, aw * inv};
    __builtin_nontemporal_store(o, reinterpret_cast<f32x4*>(out + (size_t)w * C_OUT + lane * 4));
  }
}

// ---------------------------------------------------------------------------
extern "C" void kernel_launch(void* const* d_in, const int* in_sizes, int n_in,
                              void* d_out, int out_size, void* d_ws, size_t ws_size,
                              hipStream_t stream) {
  const float* h    = (const float*)d_in[0];
  const float* Wm   = (const float*)d_in[1];
  const float* attn = (const float*)d_in[2];
  const int* e_src  = (const int*)d_in[3];
  const int* e_dst  = (const int*)d_in[4];
  float* out = (float*)d_out;

  const int N = in_sizes[0] / K_IN;
  const int E = in_sizes[3];
  const int NBK = (N + BKT - 1) / BKT;

  char* p = (char*)d_ws;
  unsigned short* zb = (unsigned short*)p; p += (size_t)N * C_OUT * sizeof(unsigned short);
  float* ssrc = (float*)p; p += (size_t)N * HEADS * sizeof(float);
  float* sdst = (float*)p; p += (size_t)N * HEADS * sizeof(float);
  int* counts = (int*)p;   p += (size_t)N * sizeof(int);
  unsigned short* Wf2 = (unsigned short*)p; p += 65536 * sizeof(unsigned short);
  int* csrp   = (int*)p;   p += (size_t)N * PAD * sizeof(int);
  int* cursors = (int*)p;  p += (size_t)NBK * REP * sizeof(int);
  int* stage   = (int*)p;
  const size_t need_binned = (size_t)(p - (char*)d_ws) + (size_t)NBK * REP * CAP * sizeof(int);
  const bool binned = ws_size >= need_binned;

  const int g_gemm = (N + 63) / 64;
  const int g_scat = ((E >> 2) + 255) / 256;

  // 0) W conversion (k-slice-contiguous layout)
  hipLaunchKernelGGL(cvt_w, dim3(256), dim3(256), 0, stream, Wm, Wf2);

  if (binned) {
    (void)hipMemsetAsync(cursors, 0, (size_t)NBK * REP * sizeof(int), stream);
    const int gmax = (g_gemm > g_scat ? g_gemm : g_scat);
    hipLaunchKernelGGL(gemm_scatter, dim3(2 * gmax), dim3(256), 0, stream,
                       h, Wf2, attn, zb, ssrc, sdst, N, g_gemm,
                       e_src, e_dst, E, g_scat, cursors, stage);
    hipLaunchKernelGGL(scatter_r2, dim3(NBK), dim3(256), 0, stream,
                       cursors, stage, N, counts, csrp);
  } else {
    hipLaunchKernelGGL(gemm_scatter, dim3(2 * g_gemm), dim3(256), 0, stream,
                       h, Wf2, attn, zb, ssrc, sdst, N, g_gemm,
                       e_src, e_dst, 0, 0, (int*)nullptr, (int*)nullptr);
    (void)hipMemsetAsync(counts, 0, (size_t)N * sizeof(int), stream);
    hipLaunchKernelGGL(scatter_pad, dim3(g_scat), dim3(256), 0, stream,
                       e_src, e_dst, E, counts, csrp);
  }

  // aggregation: single dispatch, grid-stride (2048 blocks = 8192 waves)
  int ablocks = (N + 3) / 4;
  if (ablocks > 2048) ablocks = 2048;
  hipLaunchKernelGGL(aggregate, dim3(ablocks), dim3(256), 0, stream,
                     zb, ssrc, sdst, counts, csrp, out, N);
}

// Round 19
// 258.121 us; speedup vs baseline: 1.0570x; 1.0570x over previous
//
#include <hip/hip_runtime.h>

#define K_IN   256
#define C_OUT  256
#define HEADS  4
#define PAD    64    // csr slots per node (P(deg>64) ~ 1e-13 for Poisson(16))
#define BKT    256   // dst nodes per bucket
#define REP    16    // cursor replicas per bucket
#define CAP    448   // stage capacity per (bucket, replica); avg fill ~256

typedef __attribute__((ext_vector_type(8))) short s16x8;
typedef __attribute__((ext_vector_type(4))) short s16x4;
typedef __attribute__((ext_vector_type(4))) float f32x4;
typedef __attribute__((ext_vector_type(4))) int   i32x4;

static __device__ __forceinline__ unsigned short f2bf(float f) {
  union { float f; unsigned u; } v; v.f = f;
  unsigned r = v.u + 0x7FFFu + ((v.u >> 16) & 1u);
  return (unsigned short)(r >> 16);
}
static __device__ __forceinline__ float bf2f(unsigned short u) {
  union { unsigned u; float f; } v; v.u = (unsigned)u << 16;
  return v.f;
}
static __device__ __forceinline__ unsigned cvt_pk_bf16(float lo, float hi) {
  unsigned r;
  asm volatile("v_cvt_pk_bf16_f32 %0, %1, %2" : "=v"(r) : "v"(lo), "v"(hi));
  return r;
}
static __device__ __forceinline__ float fast_exp2(float x) {
  float r;
  asm("v_exp_f32 %0, %1" : "=v"(r) : "v"(x));
  return r;
}
// async global->LDS DMA, 16B per lane; LDS dest is wave-uniform base + lane*16
static __device__ __forceinline__ void gl_lds16(const unsigned short* g, void* l) {
  __builtin_amdgcn_global_load_lds(
      (__attribute__((address_space(1))) void*)g,
      (__attribute__((address_space(3))) void*)l, 16, 0, 0);
}

// ---------------------------------------------------------------------------
// W (fp32 [c=256][k=256], c=head*64+out) -> k-slice-contiguous fragment bf16:
// Wf2[ks*8192 + cb*2048 + s*512 + lane*8 + j]
//   = W[cb*64+s*16+(lane&15)][ks*32+(lane>>4)*8+j]
// Also zeroes the scatter cursors (ncur ints) to save a memset dispatch.
// ---------------------------------------------------------------------------
__global__ void cvt_w(const float* __restrict__ Wm, unsigned short* __restrict__ Wf2,
                      int* __restrict__ cursors, int ncur) {
  int idx = blockIdx.x * blockDim.x + threadIdx.x;
  if (idx < ncur) cursors[idx] = 0;
  if (idx >= 65536) return;
  int j    = idx & 7;
  int lane = (idx >> 3) & 63;
  int s    = (idx >> 9) & 3;
  int cb   = (idx >> 11) & 3;
  int ks   = (idx >> 13) & 7;
  int c = cb * 64 + s * 16 + (lane & 15);
  int k = ks * 32 + (lane >> 4) * 8 + j;
  Wf2[idx] = f2bf(Wm[c * K_IN + k]);
}

// ---------------------------------------------------------------------------
// GEMM body (row-split, global_load_lds-staged B, full A-row prefetch):
// block = 64 rows; wave w owns rows w*16..+16, ALL 256 cols. B k-slices
// (16 KB) double-buffered in LDS via async DMA (no VGPR round-trip); DMA for
// slice ks+1 issues BEFORE the MFMA block; __syncthreads' vmcnt(0) drain
// guarantees completion before the next step reads it.
// ---------------------------------------------------------------------------
static __device__ __forceinline__ void gemm_body(int bid,
    const float* __restrict__ h, const unsigned short* __restrict__ Wf2,
    const float* __restrict__ attn, unsigned short* __restrict__ zb,
    float* __restrict__ ssrc, float* __restrict__ sdst, int n_nodes,
    s16x8 (*lds_b)[1024]) {
  const int tid  = threadIdx.x;
  const int wv   = tid >> 6;
  const int lane = tid & 63;
  const int l15  = lane & 15;
  const int lhi  = lane >> 4;
  const int r0   = bid * 64 + wv * 16;

  f32x4 acc[16];
#pragma unroll
  for (int f = 0; f < 16; ++f) acc[f] = (f32x4){0.f, 0.f, 0.f, 0.f};

  int n = r0 + l15;
  if (n > n_nodes - 1) n = n_nodes - 1;
  const long long arow = (long long)n * K_IN;
  const int kbase = lhi * 8;

  // ---- stage B slice 0 via async DMA (issues first, fills while A flies) --
#pragma unroll
  for (int r = 0; r < 4; ++r)
    gl_lds16(Wf2 + (size_t)(r * 256 + tid) * 8, &lds_b[0][r * 256 + wv * 64]);

  // ---- prefetch all 8 A slices (16 independent float4 loads in flight) ----
  float4 va[8][2];
#pragma unroll
  for (int ks = 0; ks < 8; ++ks) {
    const float4* ps = reinterpret_cast<const float4*>(h + arow + ks * 32 + kbase);
    va[ks][0] = ps[0];
    va[ks][1] = ps[1];
  }
  // convert A to bf16 fragments
  s16x8 afr[8];
#pragma unroll
  for (int ks = 0; ks < 8; ++ks) {
    union { s16x8 v; unsigned u[4]; } au;
    au.u[0] = cvt_pk_bf16(va[ks][0].x, va[ks][0].y);
    au.u[1] = cvt_pk_bf16(va[ks][0].z, va[ks][0].w);
    au.u[2] = cvt_pk_bf16(va[ks][1].x, va[ks][1].y);
    au.u[3] = cvt_pk_bf16(va[ks][1].z, va[ks][1].w);
    afr[ks] = au.v;
  }
  __syncthreads();   // drains vmcnt: slice-0 DMA + A loads complete

#pragma unroll
  for (int ks = 0; ks < 8; ++ks) {
    const int cur = ks & 1;
    // issue async DMA for next slice BEFORE compute (T14 issue-early)
    if (ks < 7) {
      const unsigned short* src = Wf2 + (size_t)(ks + 1) * 8192;
#pragma unroll
      for (int r = 0; r < 4; ++r)
        gl_lds16(src + (size_t)(r * 256 + tid) * 8, &lds_b[cur ^ 1][r * 256 + wv * 64]);
    }
#pragma unroll
    for (int f = 0; f < 16; ++f) {
      s16x8 b = lds_b[cur][f * 64 + lane];
      acc[f] = __builtin_amdgcn_mfma_f32_16x16x32_bf16(afr[ks], b, acc[f], 0, 0, 0);
    }
    if (ks < 7) __syncthreads();   // waits DMA (vmcnt) + all reads of cur done
  }

  // epilogue 1: bf16 z store
#pragma unroll
  for (int reg = 0; reg < 4; ++reg) {
    int row = r0 + lhi * 4 + reg;
    if (row < n_nodes) {
#pragma unroll
      for (int f = 0; f < 16; ++f)
        zb[(size_t)row * C_OUT + f * 16 + l15] = f2bf(acc[f][reg]);
    }
  }

  // epilogue 2: per-head scores, log2e-prescaled
  const float LOG2E = 1.4426950408889634f;
  float as_[4], ad_[4];
#pragma unroll
  for (int s = 0; s < 4; ++s) {
    as_[s] = attn[s * 16 + l15];
    ad_[s] = attn[64 + s * 16 + l15];
  }
#pragma unroll
  for (int reg = 0; reg < 4; ++reg) {
    int row = r0 + lhi * 4 + reg;
    float ps[4], pd[4];
#pragma unroll
    for (int hd = 0; hd < 4; ++hd) {
      ps[hd] = acc[hd * 4 + 0][reg] * as_[0] + acc[hd * 4 + 1][reg] * as_[1] +
               acc[hd * 4 + 2][reg] * as_[2] + acc[hd * 4 + 3][reg] * as_[3];
      pd[hd] = acc[hd * 4 + 0][reg] * ad_[0] + acc[hd * 4 + 1][reg] * ad_[1] +
               acc[hd * 4 + 2][reg] * ad_[2] + acc[hd * 4 + 3][reg] * ad_[3];
#pragma unroll
      for (int d = 1; d < 16; d <<= 1) {
        ps[hd] += __shfl_xor(ps[hd], d, 64);
        pd[hd] += __shfl_xor(pd[hd], d, 64);
      }
    }
    if (l15 == 0 && row < n_nodes) {
#pragma unroll
      for (int hd = 0; hd < 4; ++hd) {
        ssrc[(size_t)row * 4 + hd] = ps[hd] * LOG2E;
        sdst[(size_t)row * 4 + hd] = pd[hd] * LOG2E;
      }
    }
  }
}

// ---------------------------------------------------------------------------
// Scatter-r1 body (R12-proven): 4 edges/thread, append to dst buckets.
// ---------------------------------------------------------------------------
static __device__ __forceinline__ void scatter_body(int sbid,
    const int* __restrict__ src, const int* __restrict__ dst, int E,
    int* __restrict__ cursors, int* __restrict__ stage) {
  int i = sbid * 256 + threadIdx.x;
  int rep = sbid & (REP - 1);
  int e4 = E >> 2;
  if (i < e4) {
    i32x4 d = __builtin_nontemporal_load(reinterpret_cast<const i32x4*>(dst) + i);
    i32x4 s = __builtin_nontemporal_load(reinterpret_cast<const i32x4*>(src) + i);
#pragma unroll
    for (int k = 0; k < 4; ++k) {
      int c = (d[k] >> 8) * REP + rep;
      int p = atomicAdd(&cursors[c], 1);
      if (p < CAP) stage[c * CAP + p] = (s[k] << 8) | (d[k] & 255);
    }
  }
  if (i < (E & 3)) {
    int j = (e4 << 2) + i;
    int dd = dst[j], ss = src[j];
    int c = (dd >> 8) * REP + rep;
    int p = atomicAdd(&cursors[c], 1);
    if (p < CAP) stage[c * CAP + p] = (ss << 8) | (dd & 255);
  }
}

// ---------------------------------------------------------------------------
// Fused dispatch (parity interleave): even blocks gemm, odd scatter.
// ---------------------------------------------------------------------------
__global__ __launch_bounds__(256) void gemm_scatter(
    const float* __restrict__ h, const unsigned short* __restrict__ Wf2,
    const float* __restrict__ attn, unsigned short* __restrict__ zb,
    float* __restrict__ ssrc, float* __restrict__ sdst, int n_nodes,
    int g_gemm, const int* __restrict__ e_src, const int* __restrict__ e_dst,
    int E, int g_scat, int* __restrict__ cursors, int* __restrict__ stage) {
  __shared__ s16x8 lds_b[2][1024];   // 2 x 16 KB B k-slice double buffer
  int bid = blockIdx.x;
  if ((bid & 1) == 0) {
    int g = bid >> 1;
    if (g < g_gemm)
      gemm_body(g, h, Wf2, attn, zb, ssrc, sdst, n_nodes, lds_b);
  } else {
    int s = bid >> 1;
    if (s < g_scat)
      scatter_body(s, e_src, e_dst, E, cursors, stage);
  }
}

// ---------------------------------------------------------------------------
// Binned CSR build, round 2: one block per bucket; LDS counters; L2-dense
// scatter into the bucket's 64KB csrp window. Writes counts[] directly.
// ---------------------------------------------------------------------------
__global__ __launch_bounds__(256) void scatter_r2(const int* __restrict__ cursors,
                                                  const int* __restrict__ stage,
                                                  int N, int* __restrict__ counts,
                                                  int* __restrict__ csrp) {
  int b = blockIdx.x;
  int base = b << 8;
  __shared__ int cnt[BKT];
  for (int i = threadIdx.x; i < BKT; i += 256) cnt[i] = 0;
  __syncthreads();
  for (int rep = 0; rep < REP; ++rep) {
    int c = b * REP + rep;
    int len = min(cursors[c], CAP);
    for (int j = threadIdx.x; j < len; j += 256) {
      int v = stage[c * CAP + j];
      int d = v & 255, s = v >> 8;
      int slot = atomicAdd(&cnt[d], 1);
      if (slot < PAD) csrp[(size_t)(base + d) * PAD + slot] = s;
    }
  }
  __syncthreads();
  for (int i = threadIdx.x; i < BKT; i += 256) {
    int n = base + i;
    if (n < N) counts[n] = min(cnt[i], PAD);
  }
}

// ---------------------------------------------------------------------------
// Fallback: direct padded scatter (R9 path; needs less workspace)
// ---------------------------------------------------------------------------
__global__ void scatter_pad(const int* __restrict__ src, const int* __restrict__ dst,
                            int e, int* __restrict__ cursor, int* __restrict__ csrp) {
  int i = blockIdx.x * blockDim.x + threadIdx.x;
  int e4 = e >> 2;
  if (i < e4) {
    i32x4 d = __builtin_nontemporal_load(reinterpret_cast<const i32x4*>(dst) + i);
    i32x4 s = __builtin_nontemporal_load(reinterpret_cast<const i32x4*>(src) + i);
#pragma unroll
    for (int k = 0; k < 4; ++k) {
      int p = atomicAdd(&cursor[d[k]], 1);
      csrp[d[k] * PAD + p] = s[k];
    }
  }
  if (i < (e & 3)) {
    int j = (e4 << 2) + i;
    int p = atomicAdd(&cursor[dst[j]], 1);
    csrp[dst[j] * PAD + p] = src[j];
  }
}

// ---------------------------------------------------------------------------
// Aggregation (R17-proven): one wave per dst node; x8-unrolled bf16 gather;
// padded CSR; node range [n0,n1) -> two balanced dispatches.
// ---------------------------------------------------------------------------
__global__ __launch_bounds__(256) void aggregate(const unsigned short* __restrict__ zb,
                                                 const float* __restrict__ ssrc,
                                                 const float* __restrict__ sdst,
                                                 const int* __restrict__ cnts,
                                                 const int* __restrict__ csr,
                                                 float* __restrict__ out,
                                                 int n0, int n1) {
  int w = n0 + blockIdx.x * (blockDim.x >> 6) + (threadIdx.x >> 6);
  if (w >= n1) return;
  int lane = threadIdx.x & 63;
  int head = lane >> 4;
  int beg = w * PAD;
  int end = beg + cnts[w];
  float sd = sdst[(size_t)w * 4 + head];
  float ax = 0.f, ay = 0.f, az = 0.f, aw = 0.f;
  float den = 0.f;
  for (int e = beg; e < end; e += 8) {
    int srcs[8];
#pragma unroll
    for (int j = 0; j < 8; ++j) {
      int idx = e + j;
      if (idx >= end) idx = end - 1;
      srcs[j] = __builtin_nontemporal_load(csr + idx);
    }
    float ss[8];
#pragma unroll
    for (int j = 0; j < 8; ++j)
      ss[j] = ssrc[(size_t)srcs[j] * 4 + head];
    s16x4 zv[8];
#pragma unroll
    for (int j = 0; j < 8; ++j)
      zv[j] = *reinterpret_cast<const s16x4*>(zb + (size_t)srcs[j] * C_OUT + lane * 4);
#pragma unroll
    for (int j = 0; j < 8; ++j) {
      float x = ss[j] + sd;
      x = x > 0.f ? x : 0.01f * x;
      float ex = fast_exp2(x);
      ex = (e + j < end) ? ex : 0.f;
      den += ex;
      ax += ex * bf2f((unsigned short)zv[j][0]);
      ay += ex * bf2f((unsigned short)zv[j][1]);
      az += ex * bf2f((unsigned short)zv[j][2]);
      aw += ex * bf2f((unsigned short)zv[j][3]);
    }
  }
  float inv = (end > beg) ? 1.f / fmaxf(den, 1e-9f) : 0.f;
  f32x4 o = {ax * inv, ay * inv, az * inv, aw * inv};
  __builtin_nontemporal_store(o, reinterpret_cast<f32x4*>(out + (size_t)w * C_OUT + lane * 4));
}

// ---------------------------------------------------------------------------
extern "C" void kernel_launch(void* const* d_in, const int* in_sizes, int n_in,
                              void* d_out, int out_size, void* d_ws, size_t ws_size,
                              hipStream_t stream) {
  const float* h    = (const float*)d_in[0];
  const float* Wm   = (const float*)d_in[1];
  const float* attn = (const float*)d_in[2];
  const int* e_src  = (const int*)d_in[3];
  const int* e_dst  = (const int*)d_in[4];
  float* out = (float*)d_out;

  const int N = in_sizes[0] / K_IN;
  const int E = in_sizes[3];
  const int NBK = (N + BKT - 1) / BKT;

  char* p = (char*)d_ws;
  unsigned short* zb = (unsigned short*)p; p += (size_t)N * C_OUT * sizeof(unsigned short);
  float* ssrc = (float*)p; p += (size_t)N * HEADS * sizeof(float);
  float* sdst = (float*)p; p += (size_t)N * HEADS * sizeof(float);
  int* counts = (int*)p;   p += (size_t)N * sizeof(int);
  unsigned short* Wf2 = (unsigned short*)p; p += 65536 * sizeof(unsigned short);
  int* csrp   = (int*)p;   p += (size_t)N * PAD * sizeof(int);
  int* cursors = (int*)p;  p += (size_t)NBK * REP * sizeof(int);
  int* stage   = (int*)p;
  const size_t need_binned = (size_t)(p - (char*)d_ws) + (size_t)NBK * REP * CAP * sizeof(int);
  const bool binned = ws_size >= need_binned;

  const int g_gemm = (N + 63) / 64;
  const int g_scat = ((E >> 2) + 255) / 256;

  // 0) W conversion (k-slice layout) + cursor zeroing (binned path only)
  hipLaunchKernelGGL(cvt_w, dim3(256), dim3(256), 0, stream, Wm, Wf2,
                     cursors, binned ? NBK * REP : 0);

  if (binned) {
    const int gmax = (g_gemm > g_scat ? g_gemm : g_scat);
    hipLaunchKernelGGL(gemm_scatter, dim3(2 * gmax), dim3(256), 0, stream,
                       h, Wf2, attn, zb, ssrc, sdst, N, g_gemm,
                       e_src, e_dst, E, g_scat, cursors, stage);
    hipLaunchKernelGGL(scatter_r2, dim3(NBK), dim3(256), 0, stream,
                       cursors, stage, N, counts, csrp);
  } else {
    hipLaunchKernelGGL(gemm_scatter, dim3(2 * g_gemm), dim3(256), 0, stream,
                       h, Wf2, attn, zb, ssrc, sdst, N, g_gemm,
                       e_src, e_dst, 0, 0, (int*)nullptr, (int*)nullptr);
    (void)hipMemsetAsync(counts, 0, (size_t)N * sizeof(int), stream);
    hipLaunchKernelGGL(scatter_pad, dim3(g_scat), dim3(256), 0, stream,
                       e_src, e_dst, E, counts, csrp);
  }

  // aggregation, split in two balanced dispatches (R17-proven config)
  const int half = N / 2;
  hipLaunchKernelGGL(aggregate, dim3((half + 3) / 4), dim3(256), 0, stream,
                     zb, ssrc, sdst, counts, csrp, out, 0, half);
  hipLaunchKernelGGL(aggregate, dim3((N - half + 3) / 4), dim3(256), 0, stream,
                     zb, ssrc, sdst, counts, csrp, out, half, N);
}